// Round 2
// baseline (63.416 us; speedup 1.0000x reference)
//
#include <hip/hip_runtime.h>

#define ROWS   1024
#define COLS   32768
#define BLOCK  1024
#define NWAVE  (BLOCK / 64)      // 16 waves per block
#define VEC    32                // elements per thread: 1024*32 = 32768 = whole row

__global__ __launch_bounds__(BLOCK) void cumprod_row_onepass_kernel(
    const float* __restrict__ x, float* __restrict__ out) {
    __shared__ float s_wave[NWAVE];

    const int row  = blockIdx.x;
    const int tid  = threadIdx.x;
    const int lane = tid & 63;
    const int wave = tid >> 6;

    const float* __restrict__ xrow = x   + (size_t)row * COLS;
    float* __restrict__       orow = out + (size_t)row * COLS;

    // Each thread owns 32 contiguous elements. 8x float4 loads issued up
    // front (deep MLP); in-place product chain keeps VGPR use ~VEC.
    float p[VEC];
    const float4* __restrict__ src = reinterpret_cast<const float4*>(xrow + tid * VEC);
    #pragma unroll
    for (int j = 0; j < VEC / 4; ++j) {
        float4 t = src[j];
        p[4*j + 0] = t.x;
        p[4*j + 1] = t.y;
        p[4*j + 2] = t.z;
        p[4*j + 3] = t.w;
    }
    #pragma unroll
    for (int i = 1; i < VEC; ++i) p[i] *= p[i - 1];

    // Wave-level inclusive scan (product) of per-thread totals.
    float incl = p[VEC - 1];
    #pragma unroll
    for (int d = 1; d < 64; d <<= 1) {
        float o = __shfl_up(incl, d, 64);
        if (lane >= d) incl *= o;
    }
    float excl = __shfl_up(incl, 1, 64);
    if (lane == 0) excl = 1.0f;

    // Cross-wave combine: one barrier for the whole row.
    if (lane == 63) s_wave[wave] = incl;
    __syncthreads();

    float wpre = 1.0f;
    #pragma unroll
    for (int w = 0; w < NWAVE; ++w) {
        float v = s_wave[w];          // same addr across wave -> LDS broadcast
        wpre *= (w < wave) ? v : 1.0f;
    }

    const float pref = wpre * excl;

    float4* __restrict__ dst = reinterpret_cast<float4*>(orow + tid * VEC);
    #pragma unroll
    for (int j = 0; j < VEC / 4; ++j) {
        float4 o;
        o.x = pref * p[4*j + 0];
        o.y = pref * p[4*j + 1];
        o.z = pref * p[4*j + 2];
        o.w = pref * p[4*j + 3];
        dst[j] = o;
    }
}

extern "C" void kernel_launch(void* const* d_in, const int* in_sizes, int n_in,
                              void* d_out, int out_size, void* d_ws, size_t ws_size,
                              hipStream_t stream) {
    const float* x = (const float*)d_in[0];
    float* out     = (float*)d_out;
    cumprod_row_onepass_kernel<<<dim3(ROWS), dim3(BLOCK), 0, stream>>>(x, out);
}

// Round 3
// 38.167 us; speedup vs baseline: 1.6615x; 1.6615x over previous
//
#include <hip/hip_runtime.h>

#define ROWS   1024
#define COLS   32768
#define BLOCK  256
#define NWAVE  (BLOCK / 64)      // 4 waves per block
#define VEC    8                 // elements per thread per tile
#define TILE   (BLOCK * VEC)     // 2048 elements per tile
#define NTILES (COLS / TILE)     // 16 tiles per row

__device__ __forceinline__ void load_tile(const float* __restrict__ p,
                                          float4& a, float4& b) {
    a = *reinterpret_cast<const float4*>(p);
    b = *reinterpret_cast<const float4*>(p + 4);
}

__global__ __launch_bounds__(BLOCK) void cumprod_pipe_kernel(
    const float* __restrict__ x, float* __restrict__ out) {
    // Double-buffered wave totals: one raw barrier per round, no vmcnt drain.
    __shared__ float s_wave[2][NWAVE];

    const int row  = blockIdx.x;
    const int tid  = threadIdx.x;
    const int lane = tid & 63;
    const int wave = tid >> 6;

    const float* __restrict__ xrow = x   + (size_t)row * COLS;
    float* __restrict__       orow = out + (size_t)row * COLS;
    const float* __restrict__ base = xrow + tid * VEC;

    float carry = 1.0f;

    // Prologue: tiles 0 and 1 in flight / in regs.
    float4 a0, b0, a1, b1;
    load_tile(base + 0 * TILE, a0, b0);
    load_tile(base + 1 * TILE, a1, b1);

    for (int t = 0; t < NTILES; ++t) {
        // Issue prefetch for tile t+2 first — stays in flight across the
        // barrier below (raw s_barrier: no vmcnt(0) drain).
        float4 an, bn;
        const int tp = (t + 2 < NTILES) ? (t + 2) : t;  // clamped tail reload (L1-hot)
        load_tile(base + tp * TILE, an, bn);

        // Local inclusive product chain over this thread's 8 elements.
        float p0 = a0.x;
        float p1 = p0 * a0.y;
        float p2 = p1 * a0.z;
        float p3 = p2 * a0.w;
        float p4 = p3 * b0.x;
        float p5 = p4 * b0.y;
        float p6 = p5 * b0.z;
        float p7 = p6 * b0.w;

        // Wave-level inclusive scan (product) of per-thread totals.
        float incl = p7;
        #pragma unroll
        for (int d = 1; d < 64; d <<= 1) {
            float o = __shfl_up(incl, d, 64);
            if (lane >= d) incl *= o;
        }
        float excl = __shfl_up(incl, 1, 64);
        if (lane == 0) excl = 1.0f;

        // Cross-wave combine through LDS. LDS-only ordering: lgkmcnt(0) +
        // raw s_barrier — global prefetch loads are NOT drained.
        const int buf = t & 1;
        if (lane == 63) s_wave[buf][wave] = incl;
        asm volatile("s_waitcnt lgkmcnt(0)" ::: "memory");
        __builtin_amdgcn_s_barrier();
        asm volatile("" ::: "memory");

        float wpre = 1.0f;   // product of earlier waves' totals (this tile)
        float btot = 1.0f;   // whole-tile product
        #pragma unroll
        for (int w = 0; w < NWAVE; ++w) {
            float v = s_wave[buf][w];   // broadcast read
            wpre *= (w < wave) ? v : 1.0f;
            btot *= v;
        }

        const float pref = carry * wpre * excl;

        float4 o0, o1;
        o0.x = pref * p0; o0.y = pref * p1; o0.z = pref * p2; o0.w = pref * p3;
        o1.x = pref * p4; o1.y = pref * p5; o1.z = pref * p6; o1.w = pref * p7;
        float* __restrict__ dstp = orow + t * TILE + tid * VEC;
        *reinterpret_cast<float4*>(dstp)     = o0;
        *reinterpret_cast<float4*>(dstp + 4) = o1;

        carry *= btot;

        // Rotate the prefetch pipeline.
        a0 = a1; b0 = b1;
        a1 = an; b1 = bn;
    }
}

extern "C" void kernel_launch(void* const* d_in, const int* in_sizes, int n_in,
                              void* d_out, int out_size, void* d_ws, size_t ws_size,
                              hipStream_t stream) {
    const float* x = (const float*)d_in[0];
    float* out     = (float*)d_out;
    cumprod_pipe_kernel<<<dim3(ROWS), dim3(BLOCK), 0, stream>>>(x, out);
}